// Round 1
// baseline (5478.014 us; speedup 1.0000x reference)
//
#include <hip/hip_runtime.h>

// ChainMessagePassing: out = scatter_add(x[up_src] -> up_dst) + scatter_add(x[down_src] -> down_dst)
// x: [N=100000, D=64] fp32; up/down_index: [2, E=3200000] int (src row 0, dst row 1)

static constexpr int D_FEAT = 64;
static constexpr int QUADS = D_FEAT / 4;  // 16 float4 quads per feature row

// Device-side index-dtype sniffer: int64 little-endian nonneg values < 2^31
// have all-zero high dwords. 128 consecutive random int32 values in
// [0,100000) being zero at every odd word is impossible (p ~ 1e-320).
__global__ void detect_idx_dtype(const int* __restrict__ idx_words, int* __restrict__ flag) {
    if (blockIdx.x == 0 && threadIdx.x == 0) {
        int is64 = 1;
        for (int i = 1; i < 256; i += 2) {
            if (idx_words[i] != 0) { is64 = 0; break; }
        }
        *flag = is64;
    }
}

__global__ __launch_bounds__(256) void scatter_add_kernel(
        const float* __restrict__ x,
        const void* __restrict__ up_idx,
        const void* __restrict__ down_idx,
        float* __restrict__ out,
        const int* __restrict__ dtype_flag,
        int num_edges) {
    const int is64 = *dtype_flag;  // wave-uniform, L2-hit
    const long long total = 2LL * num_edges * QUADS;
    const long long stride = (long long)gridDim.x * blockDim.x;

    for (long long t = (long long)blockIdx.x * blockDim.x + threadIdx.x;
         t < total; t += stride) {
        const int quad = (int)(t & (QUADS - 1));
        long long eg = t >> 4;  // edge slot across both graphs: 0..2E-1
        const void* idx = up_idx;
        if (eg >= num_edges) { idx = down_idx; eg -= num_edges; }

        int src, dst;
        if (is64) {
            const long long* p = (const long long*)idx;
            src = (int)p[eg];
            dst = (int)p[num_edges + eg];
        } else {
            const int* p = (const int*)idx;
            src = p[eg];
            dst = p[num_edges + eg];
        }

        // Coalesced 256B row gather across the 16-thread edge group.
        const float4 v = *(const float4*)(x + (long long)src * D_FEAT + quad * 4);
        float* o = out + (long long)dst * D_FEAT + quad * 4;
        // HW fp32 atomics (global_atomic_add_f32), not CAS loops.
        unsafeAtomicAdd(o + 0, v.x);
        unsafeAtomicAdd(o + 1, v.y);
        unsafeAtomicAdd(o + 2, v.z);
        unsafeAtomicAdd(o + 3, v.w);
    }
}

extern "C" void kernel_launch(void* const* d_in, const int* in_sizes, int n_in,
                              void* d_out, int out_size, void* d_ws, size_t ws_size,
                              hipStream_t stream) {
    const float* x = (const float*)d_in[0];
    const void* up_idx = d_in[1];
    const void* down_idx = d_in[2];
    float* out = (float*)d_out;
    int* dtype_flag = (int*)d_ws;

    const int num_edges = in_sizes[1] / 2;  // [2, E] flat element count

    // Output accumulates via atomics; harness poisons it to 0xAA each call.
    hipMemsetAsync(d_out, 0, (size_t)out_size * sizeof(float), stream);

    detect_idx_dtype<<<1, 1, 0, stream>>>((const int*)up_idx, dtype_flag);

    const int block = 256;
    const int grid = 8192;  // grid-stride over 2*E*16 = 102.4M work items
    scatter_add_kernel<<<grid, block, 0, stream>>>(
        x, up_idx, down_idx, out, dtype_flag, num_edges);
}

// Round 2
// 1344.507 us; speedup vs baseline: 4.0744x; 4.0744x over previous
//
#include <hip/hip_runtime.h>

// ChainMessagePassing: out[n] = sum_{e: up_dst[e]==n} x[up_src[e]] + sum_{e: down_dst[e]==n} x[down_src[e]]
// x: [N=100000, 64] fp32; indices: [2, E=3200000], src row 0, dst row 1.
//
// Strategy: per-call counting sort of the combined 2E edges by dst
// (histogram -> single-block scan -> bin scatter), then an atomic-free
// gather: 16 threads per node accumulate float4 quads over the node's
// incoming edge list. Replaces 409.6M fp32 device atomics (R1: 6.5 GB of
// 16B atomic transactions, 5.4 ms) with 12.8M int atomics into 400 KB.

static constexpr int D = 64;
static constexpr int Q = 16;  // float4 quads per feature row

// ---- index dtype sniffer: int64 nonneg <2^31 has all-zero odd dwords ----
__global__ void detect_idx_dtype(const int* __restrict__ w, int* __restrict__ flag) {
    int tid = threadIdx.x;  // one wave
    int v = w[2 * tid + 1];
    unsigned long long m = __ballot(v != 0);
    if (tid == 0) *flag = (m == 0ULL) ? 1 : 0;
}

__device__ __forceinline__ int load_idx(const void* idx, long long i, int is64) {
    return is64 ? (int)((const long long*)idx)[i] : ((const int*)idx)[i];
}

// ---- phase 1: histogram of destinations over both edge lists ----
__global__ __launch_bounds__(256) void hist_kernel(
        const void* __restrict__ up, const void* __restrict__ down,
        int* __restrict__ counts, const int* __restrict__ flag, int E) {
    const int is64 = *flag;
    const long long total = 2LL * E;
    const long long stride = (long long)gridDim.x * blockDim.x;
    for (long long e = (long long)blockIdx.x * blockDim.x + threadIdx.x;
         e < total; e += stride) {
        const void* idx = up;
        long long ee = e;
        if (ee >= E) { idx = down; ee -= E; }
        int dst = load_idx(idx, E + ee, is64);
        atomicAdd(&counts[dst], 1);
    }
}

// ---- phase 2: exclusive scan, one block of 1024 threads ----
__global__ __launch_bounds__(1024) void scan_kernel(
        const int* __restrict__ counts, int* __restrict__ offsets,
        int* __restrict__ cursors, int N) {
    __shared__ int sums[1024];
    const int tid = threadIdx.x;
    const int chunk = (N + 1023) / 1024;
    const int start = tid * chunk;
    const int end = min(start + chunk, N);
    int s = 0;
    for (int i = start; i < end; i++) s += counts[i];
    sums[tid] = s;
    __syncthreads();
    // Hillis-Steele inclusive scan over thread sums
    for (int off = 1; off < 1024; off <<= 1) {
        int t = (tid >= off) ? sums[tid - off] : 0;
        __syncthreads();
        sums[tid] += t;
        __syncthreads();
    }
    int run = (tid == 0) ? 0 : sums[tid - 1];  // exclusive prefix of this chunk
    for (int i = start; i < end; i++) {
        offsets[i] = run;
        cursors[i] = run;
        run += counts[i];
    }
    if (tid == 1023) offsets[N] = run;  // trailing empty chunks keep run == total
}

// ---- phase 3: scatter src ids into dst-sorted bins ----
__global__ __launch_bounds__(256) void bin_scatter_kernel(
        const void* __restrict__ up, const void* __restrict__ down,
        int* __restrict__ cursors, int* __restrict__ ssrc,
        const int* __restrict__ flag, int E) {
    const int is64 = *flag;
    const long long total = 2LL * E;
    const long long stride = (long long)gridDim.x * blockDim.x;
    for (long long e = (long long)blockIdx.x * blockDim.x + threadIdx.x;
         e < total; e += stride) {
        const void* idx = up;
        long long ee = e;
        if (ee >= E) { idx = down; ee -= E; }
        int src = load_idx(idx, ee, is64);
        int dst = load_idx(idx, E + ee, is64);
        int pos = atomicAdd(&cursors[dst], 1);
        ssrc[pos] = src;
    }
}

// ---- phase 4: atomic-free gather; 16 threads per node ----
__global__ __launch_bounds__(256) void gather_kernel(
        const float* __restrict__ x, const int* __restrict__ offsets,
        const int* __restrict__ ssrc, float* __restrict__ out, int N) {
    const int t = blockIdx.x * blockDim.x + threadIdx.x;
    const int node = t >> 4;
    const int q = t & (Q - 1);
    if (node >= N) return;
    const int beg = offsets[node];
    const int end = offsets[node + 1];
    float4 acc = make_float4(0.f, 0.f, 0.f, 0.f);
    int e = beg;
    for (; e + 4 <= end; e += 4) {  // 4 independent row gathers in flight
        int s0 = ssrc[e], s1 = ssrc[e + 1], s2 = ssrc[e + 2], s3 = ssrc[e + 3];
        float4 v0 = *(const float4*)(x + (long long)s0 * D + q * 4);
        float4 v1 = *(const float4*)(x + (long long)s1 * D + q * 4);
        float4 v2 = *(const float4*)(x + (long long)s2 * D + q * 4);
        float4 v3 = *(const float4*)(x + (long long)s3 * D + q * 4);
        acc.x += v0.x + v1.x + v2.x + v3.x;
        acc.y += v0.y + v1.y + v2.y + v3.y;
        acc.z += v0.z + v1.z + v2.z + v3.z;
        acc.w += v0.w + v1.w + v2.w + v3.w;
    }
    for (; e < end; e++) {
        int s = ssrc[e];
        float4 v = *(const float4*)(x + (long long)s * D + q * 4);
        acc.x += v.x; acc.y += v.y; acc.z += v.z; acc.w += v.w;
    }
    *(float4*)(out + (long long)node * D + q * 4) = acc;
}

// ---- fallback (R1): direct fp32 atomics, needs no workspace ----
__global__ __launch_bounds__(256) void scatter_add_kernel(
        const float* __restrict__ x, const void* __restrict__ up_idx,
        const void* __restrict__ down_idx, float* __restrict__ out,
        const int* __restrict__ dtype_flag, int num_edges) {
    const int is64 = *dtype_flag;
    const long long total = 2LL * num_edges * Q;
    const long long stride = (long long)gridDim.x * blockDim.x;
    for (long long t = (long long)blockIdx.x * blockDim.x + threadIdx.x;
         t < total; t += stride) {
        const int quad = (int)(t & (Q - 1));
        long long eg = t >> 4;
        const void* idx = up_idx;
        if (eg >= num_edges) { idx = down_idx; eg -= num_edges; }
        int src = load_idx(idx, eg, is64);
        int dst = load_idx(idx, num_edges + eg, is64);
        const float4 v = *(const float4*)(x + (long long)src * D + quad * 4);
        float* o = out + (long long)dst * D + quad * 4;
        unsafeAtomicAdd(o + 0, v.x);
        unsafeAtomicAdd(o + 1, v.y);
        unsafeAtomicAdd(o + 2, v.z);
        unsafeAtomicAdd(o + 3, v.w);
    }
}

extern "C" void kernel_launch(void* const* d_in, const int* in_sizes, int n_in,
                              void* d_out, int out_size, void* d_ws, size_t ws_size,
                              hipStream_t stream) {
    const float* x = (const float*)d_in[0];
    const void* up_idx = d_in[1];
    const void* down_idx = d_in[2];
    float* out = (float*)d_out;

    const int E = in_sizes[1] / 2;     // [2, E]
    const int N = out_size / D;        // [N, 64]
    const long long Etot = 2LL * E;

    // workspace layout (ints): flag | counts[N] | offsets[N+1] | pad | cursors[N] | ssrc[2E]
    int* ws_i = (int*)d_ws;
    int* flag = ws_i;
    int* counts = ws_i + 64;
    int* offsets = counts + N;
    int* cursors = offsets + N + 15;
    int* ssrc = cursors + N;
    const size_t ws_need = (size_t)(64 + 3LL * N + 16 + Etot) * 4 + 64;

    detect_idx_dtype<<<1, 64, 0, stream>>>((const int*)up_idx, flag);

    if (ws_size >= ws_need) {
        hipMemsetAsync(counts, 0, (size_t)N * sizeof(int), stream);
        hist_kernel<<<4096, 256, 0, stream>>>(up_idx, down_idx, counts, flag, E);
        scan_kernel<<<1, 1024, 0, stream>>>(counts, offsets, cursors, N);
        bin_scatter_kernel<<<4096, 256, 0, stream>>>(up_idx, down_idx, cursors, ssrc, flag, E);
        const int gblocks = (N * Q + 255) / 256;
        gather_kernel<<<gblocks, 256, 0, stream>>>(x, offsets, ssrc, out, N);
    } else {
        hipMemsetAsync(d_out, 0, (size_t)out_size * sizeof(float), stream);
        scatter_add_kernel<<<8192, 256, 0, stream>>>(x, up_idx, down_idx, out, flag, E);
    }
}